// Round 1
// baseline (530.844 us; speedup 1.0000x reference)
//
#include <hip/hip_runtime.h>
#include <stdint.h>

#define B_N 16384
#define D_N 1024
#define H_N 4096

typedef __bf16 bf16x8 __attribute__((ext_vector_type(8)));
typedef float f32x4 __attribute__((ext_vector_type(4)));

__device__ __forceinline__ unsigned short f2bf(float f) {
  unsigned int u = __float_as_uint(f);
  u += 0x7fffu + ((u >> 16) & 1u);   // RNE
  return (unsigned short)(u >> 16);
}

__device__ __forceinline__ float fast_tanh(float x) {
  float xx = fminf(fmaxf(x, -15.0f), 15.0f);
  float e = __expf(2.0f * xx);
  return (e - 1.0f) * __builtin_amdgcn_rcpf(e + 1.0f);
}

__device__ __forceinline__ void gload16(const void* g, void* l) {
  __builtin_amdgcn_global_load_lds((const __attribute__((address_space(1))) void*)g,
                                   (__attribute__((address_space(3))) void*)l,
                                   16, 0, 0);
}

// ---- pack X fp32 -> bf16; extract s[b] = 1 - 2*X[b][pci] ----
__global__ void pack_X_kernel(const float4* __restrict__ X4,
                              ushort4* __restrict__ Xb4,
                              float* __restrict__ s,
                              const int* __restrict__ pci_p) {
  int i = blockIdx.x * 256 + threadIdx.x;
  if (i >= B_N * (D_N / 4)) return;
  float4 v = X4[i];
  ushort4 o;
  o.x = f2bf(v.x); o.y = f2bf(v.y); o.z = f2bf(v.z); o.w = f2bf(v.w);
  Xb4[i] = o;
  int pci = *pci_p;
  int colg = i & (D_N / 4 - 1);
  if (colg == (pci >> 2)) {
    int row = i >> 8;               // i / (D_N/4), D_N/4 == 256
    float c;
    switch (pci & 3) {
      case 0:  c = v.x; break;
      case 1:  c = v.y; break;
      case 2:  c = v.z; break;
      default: c = v.w; break;
    }
    s[row] = 1.0f - 2.0f * c;
  }
}

// ---- transpose + fp32->bf16 pack: out[j][i] = in[i][j]; in is R x C ----
// optionally extracts w3[j] = in[pci][j]
__global__ void transpose_pack(const float* __restrict__ in,
                               unsigned short* __restrict__ out,
                               int R, int C,
                               float* __restrict__ w3,
                               const int* __restrict__ pci_p) {
  __shared__ float tile[32][33];
  int i0 = blockIdx.y * 32;
  int j0 = blockIdx.x * 32;
  int tx = threadIdx.x, ty = threadIdx.y;  // 32 x 8
  int pci = pci_p ? *pci_p : -1;
#pragma unroll
  for (int r = 0; r < 32; r += 8) {
    int i = i0 + ty + r;
    int j = j0 + tx;
    float v = in[(size_t)i * C + j];
    tile[ty + r][tx] = v;
    if (w3 != nullptr && i == pci) w3[j] = v;
  }
  __syncthreads();
#pragma unroll
  for (int r = 0; r < 32; r += 8) {
    int jo = j0 + ty + r;
    int io = i0 + tx;
    out[(size_t)jo * R + io] = f2bf(tile[tx][ty + r]);
  }
}

// ---- GEMM1: Z = Xb @ W1  (via W1T, B^T layout), epilogue Dh = tanh(Z)-tanh(Z+s*w3) ----
__global__ __launch_bounds__(256) void gemm1_dh(
    const unsigned short* __restrict__ Xb,    // B_N x D_N bf16
    const unsigned short* __restrict__ W1T,   // H_N x D_N bf16 (W1T[h][d] = W1[d][h])
    const float* __restrict__ b1,             // H_N
    const float* __restrict__ w3,             // H_N : W1[pci][h]
    const float* __restrict__ s,              // B_N : 1-2*col
    unsigned short* __restrict__ Dh) {        // B_N x H_N bf16
  __shared__ alignas(16) unsigned short As[128 * 32];
  __shared__ alignas(16) unsigned short Bs[128 * 32];
  const int tid = threadIdx.x;
  const int lane = tid & 63;
  const int wave = tid >> 6;
  const int m0 = blockIdx.y * 128;
  const int n0 = blockIdx.x * 128;
  const int wm = (wave >> 1) * 64;
  const int wn = (wave & 1) * 64;
  const int lm = lane & 15;
  const int quad = lane >> 4;

  f32x4 acc[4][4] = {};

  const int srow = tid >> 2;          // 0..63
  const int scol = (tid & 3) * 8;     // 0,8,16,24
  const unsigned short* Ag = Xb + (size_t)(m0 + srow) * D_N + scol;
  const unsigned short* Bg = W1T + (size_t)(n0 + srow) * D_N + scol;
  unsigned short* As_l = As + tid * 8;
  unsigned short* Bs_l = Bs + tid * 8;

  for (int k0 = 0; k0 < D_N; k0 += 32) {
    gload16(Ag + k0, As_l);
    gload16(Ag + (size_t)64 * D_N + k0, As_l + 64 * 32);
    gload16(Bg + k0, Bs_l);
    gload16(Bg + (size_t)64 * D_N + k0, Bs_l + 64 * 32);
    __syncthreads();
    bf16x8 a[4], b[4];
#pragma unroll
    for (int i = 0; i < 4; i++)
      a[i] = *(const bf16x8*)&As[(wm + i * 16 + lm) * 32 + quad * 8];
#pragma unroll
    for (int j = 0; j < 4; j++)
      b[j] = *(const bf16x8*)&Bs[(wn + j * 16 + lm) * 32 + quad * 8];
#pragma unroll
    for (int i = 0; i < 4; i++)
#pragma unroll
      for (int j = 0; j < 4; j++)
        acc[i][j] = __builtin_amdgcn_mfma_f32_16x16x32_bf16(a[i], b[j], acc[i][j], 0, 0, 0);
    __syncthreads();
  }

  float w3v[4], b1v[4];
  int ghv[4];
#pragma unroll
  for (int j = 0; j < 4; j++) {
    int gh = n0 + wn + j * 16 + lm;
    ghv[j] = gh;
    w3v[j] = w3[gh];
    b1v[j] = b1[gh];
  }
#pragma unroll
  for (int i = 0; i < 4; i++) {
#pragma unroll
    for (int r = 0; r < 4; r++) {
      int gb = m0 + wm + i * 16 + quad * 4 + r;
      float sv = s[gb];
      size_t rowbase = (size_t)gb * H_N;
#pragma unroll
      for (int j = 0; j < 4; j++) {
        float z = acc[i][j][r] + b1v[j];
        float dh = fast_tanh(z) - fast_tanh(z + sv * w3v[j]);
        Dh[rowbase + ghv[j]] = f2bf(dh);
      }
    }
  }
}

// ---- GEMM2: Y = Dh @ W2 (via W2T), epilogue sum |Y| -> atomic scalar ----
__global__ __launch_bounds__(256) void gemm2_abs(
    const unsigned short* __restrict__ Dh,    // B_N x H_N bf16
    const unsigned short* __restrict__ W2T,   // D_N x H_N bf16 (W2T[d][h] = W2[h][d])
    float* __restrict__ accum) {
  __shared__ alignas(16) unsigned short As[128 * 32];
  __shared__ alignas(16) unsigned short Bs[128 * 32];
  __shared__ float wsum[4];
  const int tid = threadIdx.x;
  const int lane = tid & 63;
  const int wave = tid >> 6;
  const int m0 = blockIdx.y * 128;
  const int n0 = blockIdx.x * 128;
  const int wm = (wave >> 1) * 64;
  const int wn = (wave & 1) * 64;
  const int lm = lane & 15;
  const int quad = lane >> 4;

  f32x4 acc[4][4] = {};

  const int srow = tid >> 2;
  const int scol = (tid & 3) * 8;
  const unsigned short* Ag = Dh + (size_t)(m0 + srow) * H_N + scol;
  const unsigned short* Bg = W2T + (size_t)(n0 + srow) * H_N + scol;
  unsigned short* As_l = As + tid * 8;
  unsigned short* Bs_l = Bs + tid * 8;

  for (int k0 = 0; k0 < H_N; k0 += 32) {
    gload16(Ag + k0, As_l);
    gload16(Ag + (size_t)64 * H_N + k0, As_l + 64 * 32);
    gload16(Bg + k0, Bs_l);
    gload16(Bg + (size_t)64 * H_N + k0, Bs_l + 64 * 32);
    __syncthreads();
    bf16x8 a[4], b[4];
#pragma unroll
    for (int i = 0; i < 4; i++)
      a[i] = *(const bf16x8*)&As[(wm + i * 16 + lm) * 32 + quad * 8];
#pragma unroll
    for (int j = 0; j < 4; j++)
      b[j] = *(const bf16x8*)&Bs[(wn + j * 16 + lm) * 32 + quad * 8];
#pragma unroll
    for (int i = 0; i < 4; i++)
#pragma unroll
      for (int j = 0; j < 4; j++)
        acc[i][j] = __builtin_amdgcn_mfma_f32_16x16x32_bf16(a[i], b[j], acc[i][j], 0, 0, 0);
    __syncthreads();
  }

  float t = 0.0f;
#pragma unroll
  for (int i = 0; i < 4; i++)
#pragma unroll
    for (int j = 0; j < 4; j++)
#pragma unroll
      for (int r = 0; r < 4; r++)
        t += fabsf(acc[i][j][r]);

#pragma unroll
  for (int off2 = 32; off2 > 0; off2 >>= 1)
    t += __shfl_down(t, off2, 64);
  if (lane == 0) wsum[wave] = t;
  __syncthreads();
  if (tid == 0) atomicAdd(accum, wsum[0] + wsum[1] + wsum[2] + wsum[3]);
}

__global__ void finalize_kernel(const float* __restrict__ acc, float* __restrict__ out) {
  out[0] = acc[0] * (1.0f / (float)B_N);
}

extern "C" void kernel_launch(void* const* d_in, const int* in_sizes, int n_in,
                              void* d_out, int out_size, void* d_ws, size_t ws_size,
                              hipStream_t stream) {
  const float* X  = (const float*)d_in[0];
  const float* W1 = (const float*)d_in[1];
  const float* b1 = (const float*)d_in[2];
  const float* W2 = (const float*)d_in[3];
  // d_in[4] = b2 : cancels in the difference
  const int* pci  = (const int*)d_in[5];

  char* ws = (char*)d_ws;
  size_t off = 0;
  unsigned short* Xb  = (unsigned short*)(ws + off); off += (size_t)B_N * D_N * 2;
  unsigned short* W1T = (unsigned short*)(ws + off); off += (size_t)H_N * D_N * 2;
  unsigned short* W2T = (unsigned short*)(ws + off); off += (size_t)D_N * H_N * 2;
  float* w3  = (float*)(ws + off); off += (size_t)H_N * 4;
  float* s   = (float*)(ws + off); off += (size_t)B_N * 4;
  float* acc = (float*)(ws + off); off += 64;
  unsigned short* Dh = (unsigned short*)(ws + off); off += (size_t)B_N * H_N * 2;
  if (ws_size < off) return;  // insufficient workspace -> visible failure, will restructure

  hipMemsetAsync(acc, 0, sizeof(float), stream);
  pack_X_kernel<<<B_N * (D_N / 4) / 256, 256, 0, stream>>>((const float4*)X, (ushort4*)Xb, s, pci);
  transpose_pack<<<dim3(H_N / 32, D_N / 32), dim3(32, 8), 0, stream>>>(W1, W1T, D_N, H_N, w3, pci);
  transpose_pack<<<dim3(D_N / 32, H_N / 32), dim3(32, 8), 0, stream>>>(W2, W2T, H_N, D_N, nullptr, nullptr);
  gemm1_dh<<<dim3(H_N / 128, B_N / 128), 256, 0, stream>>>(Xb, W1T, b1, w3, s, Dh);
  gemm2_abs<<<dim3(D_N / 128, B_N / 128), 256, 0, stream>>>(Dh, W2T, acc);
  finalize_kernel<<<1, 1, 0, stream>>>(acc, (float*)d_out);
}

// Round 2
// 326.425 us; speedup vs baseline: 1.6262x; 1.6262x over previous
//
#include <hip/hip_runtime.h>
#include <stdint.h>

#define B_N 16384
#define D_N 1024
#define H_N 4096

typedef int i32x4 __attribute__((ext_vector_type(4)));
typedef int i32x8 __attribute__((ext_vector_type(8)));
typedef float f32x4 __attribute__((ext_vector_type(4)));

__device__ __forceinline__ void gload16(const void* g, void* l) {
  __builtin_amdgcn_global_load_lds((const __attribute__((address_space(1))) void*)g,
                                   (__attribute__((address_space(3))) void*)l,
                                   16, 0, 0);
}

__device__ __forceinline__ unsigned char f2fp8(float v) {
  return (unsigned char)(__builtin_amdgcn_cvt_pk_fp8_f32(v, v, 0, false) & 0xFF);
}

// ---- pack X fp32 -> fp8 e4m3 (scale 1); extract s[b] = 1 - 2*X[b][pci] ----
__global__ void pack_X_kernel(const float4* __restrict__ X4,
                              int* __restrict__ Xb,
                              float* __restrict__ s,
                              const int* __restrict__ pci_p) {
  int i = blockIdx.x * 256 + threadIdx.x;
  if (i >= B_N * (D_N / 4)) return;
  float4 v = X4[i];
  int p = __builtin_amdgcn_cvt_pk_fp8_f32(v.x, v.y, 0, false);
  p = __builtin_amdgcn_cvt_pk_fp8_f32(v.z, v.w, p, true);
  Xb[i] = p;
  int pci = *pci_p;
  int colg = i & (D_N / 4 - 1);
  if (colg == (pci >> 2)) {
    int row = i >> 8;               // i / (D_N/4), D_N/4 == 256
    float c;
    switch (pci & 3) {
      case 0:  c = v.x; break;
      case 1:  c = v.y; break;
      case 2:  c = v.z; break;
      default: c = v.w; break;
    }
    s[row] = 1.0f - 2.0f * c;
  }
}

// ---- transpose + fp32->fp8 pack with scale: out[j][i] = in[i][j]*scale ----
__global__ void transpose_pack_fp8(const float* __restrict__ in,
                                   unsigned char* __restrict__ out,
                                   int R, int C, float scale,
                                   float* __restrict__ w3,
                                   const int* __restrict__ pci_p) {
  __shared__ float tile[32][33];
  int i0 = blockIdx.y * 32;
  int j0 = blockIdx.x * 32;
  int tx = threadIdx.x, ty = threadIdx.y;  // 32 x 8
  int pci = pci_p ? *pci_p : -1;
#pragma unroll
  for (int r = 0; r < 32; r += 8) {
    int i = i0 + ty + r;
    int j = j0 + tx;
    float v = in[(size_t)i * C + j];
    tile[ty + r][tx] = v;
    if (w3 != nullptr && i == pci) w3[j] = v;
  }
  __syncthreads();
#pragma unroll
  for (int r = 0; r < 32; r += 8) {
    int jo = j0 + ty + r;
    int io = i0 + tx;
    out[(size_t)jo * R + io] = f2fp8(tile[tx][ty + r] * scale);
  }
}

// ---- MX-fp8 K=128 main loop: C(128x128) += A_tile x B_tile^T over KTOT ----
// LDS layout XOR-swizzled: LDS[r][c16] = global chunk (c16 ^ (r&7)) of row r.
// (global_load_lds dest must be lane-linear, so the swizzle is applied on the
//  per-lane GLOBAL gather address; reader XORs back. Breaks the 16-way bank
//  conflict the 128B row stride would otherwise cause.)
template <int KTOT>
__device__ __forceinline__ void mx_mainloop(
    const unsigned char* __restrict__ A, const unsigned char* __restrict__ B,
    int m0, int n0, int sa, int sb,
    unsigned char* As, unsigned char* Bs, f32x4 (&acc)[4][4]) {
  const int tid = threadIdx.x;
  const int lane = tid & 63;
  const int wave = tid >> 6;
  const int wm = (wave >> 1) * 64;
  const int wn = (wave & 1) * 64;
  const int lm = lane & 15;
  const int quad = lane >> 4;

  const int srow = tid >> 3;                 // 0..31
  const int clog = (tid & 7) ^ (srow & 7);   // swizzled global chunk
  const unsigned char* Ag = A + (size_t)(m0 + srow) * KTOT + clog * 16;
  const unsigned char* Bg = B + (size_t)(n0 + srow) * KTOT + clog * 16;
  unsigned char* As_l = As + tid * 16;
  unsigned char* Bs_l = Bs + tid * 16;

  for (int k0 = 0; k0 < KTOT; k0 += 128) {
#pragma unroll
    for (int it = 0; it < 4; it++) {
      gload16(Ag + k0 + (size_t)(32 * it) * KTOT, As_l + it * 4096);
      gload16(Bg + k0 + (size_t)(32 * it) * KTOT, Bs_l + it * 4096);
    }
    __syncthreads();
    i32x8 a[4], b[4];
#pragma unroll
    for (int i = 0; i < 4; i++) {
      int r = wm + i * 16 + lm;
      int e = r & 7;
      i32x4 lo = *(const i32x4*)&As[r * 128 + ((2 * quad) ^ e) * 16];
      i32x4 hi = *(const i32x4*)&As[r * 128 + ((2 * quad + 1) ^ e) * 16];
      a[i][0] = lo[0]; a[i][1] = lo[1]; a[i][2] = lo[2]; a[i][3] = lo[3];
      a[i][4] = hi[0]; a[i][5] = hi[1]; a[i][6] = hi[2]; a[i][7] = hi[3];
    }
#pragma unroll
    for (int j = 0; j < 4; j++) {
      int r = wn + j * 16 + lm;
      int e = r & 7;
      i32x4 lo = *(const i32x4*)&Bs[r * 128 + ((2 * quad) ^ e) * 16];
      i32x4 hi = *(const i32x4*)&Bs[r * 128 + ((2 * quad + 1) ^ e) * 16];
      b[j][0] = lo[0]; b[j][1] = lo[1]; b[j][2] = lo[2]; b[j][3] = lo[3];
      b[j][4] = hi[0]; b[j][5] = hi[1]; b[j][6] = hi[2]; b[j][7] = hi[3];
    }
#pragma unroll
    for (int i = 0; i < 4; i++)
#pragma unroll
      for (int j = 0; j < 4; j++)
        acc[i][j] = __builtin_amdgcn_mfma_scale_f32_16x16x128_f8f6f4(
            a[i], b[j], acc[i][j], 0, 0, 0, sa, 0, sb);
    __syncthreads();
  }
}

// XCD-aware tile remap: m-tile -> XCD = m_t / (MT/8) in BOTH gemms so Dh
// m-slices are produced and consumed on the same XCD's L2.
__device__ __forceinline__ void xcd_remap(int NT, int MT, int& m_t, int& n_t) {
  int l = blockIdx.y * NT + blockIdx.x;   // HW dispatch-linear id
  int x = l & 7;                          // XCD (round-robin dispatch)
  int k = l >> 3;
  m_t = x * (MT >> 3) + k / NT;
  n_t = k % NT;
}

// ---- GEMM1 (MX-fp8): Z = X @ W1, epilogue Dh = tanh(z)-tanh(z+s*w3) -> fp8*64
__global__ __launch_bounds__(256) void gemm1_dh(
    const unsigned char* __restrict__ Xb,    // B_N x D_N fp8 (x1)
    const unsigned char* __restrict__ W1T,   // H_N x D_N fp8 (x16)
    const float* __restrict__ b1,
    const float* __restrict__ w3,            // H_N : W1[pci][h] f32
    const float* __restrict__ s,             // B_N : 1-2*col
    unsigned char* __restrict__ Dh) {        // B_N x H_N fp8 (x64)
  __shared__ alignas(16) unsigned char As[128 * 128];
  __shared__ alignas(16) unsigned char Bs[128 * 128];
  int m_t, n_t;
  xcd_remap(H_N / 128, B_N / 128, m_t, n_t);
  const int m0 = m_t * 128, n0 = n_t * 128;

  f32x4 acc[4][4] = {};
  mx_mainloop<D_N>(Xb, W1T, m0, n0, 127, 123, As, Bs, acc);  // 2^0 * 2^-4

  const int tid = threadIdx.x;
  const int lane = tid & 63;
  const int wave = tid >> 6;
  const int wm = (wave >> 1) * 64;
  const int wn = (wave & 1) * 64;
  const int lm = lane & 15;
  const int quad = lane >> 4;

  float ewp[4], ewm[4], b1v[4];
  int ghv[4];
#pragma unroll
  for (int j = 0; j < 4; j++) {
    int gh = n0 + wn + j * 16 + lm;
    float w = w3[gh];
    ewp[j] = __expf(2.0f * w);
    ewm[j] = __expf(-2.0f * w);
    b1v[j] = b1[gh];
    ghv[j] = gh;
  }
#pragma unroll
  for (int i = 0; i < 4; i++) {
#pragma unroll
    for (int r = 0; r < 4; r++) {
      int gb = m0 + wm + i * 16 + quad * 4 + r;
      float sv = s[gb];
      size_t rowbase = (size_t)gb * H_N;
#pragma unroll
      for (int j = 0; j < 4; j++) {
        float z = acc[i][j][r] + b1v[j];
        z = fminf(fmaxf(z, -20.0f), 20.0f);
        float E = __expf(2.0f * z);
        float ews = (sv > 0.0f) ? ewp[j] : ewm[j];
        // tanh(z) - tanh(z+w) = 2E(1-e^{2w}) / ((E e^{2w}+1)(E+1))
        float num = 2.0f * E * (1.0f - ews);
        float den = (E * ews + 1.0f) * (E + 1.0f);
        float dh = num * __builtin_amdgcn_rcpf(den);
        Dh[rowbase + ghv[j]] = f2fp8(dh * 64.0f);
      }
    }
  }
}

// ---- GEMM2 (MX-fp8): Y = Dh @ W2, epilogue sum |Y| -> atomic scalar ----
__global__ __launch_bounds__(256) void gemm2_abs(
    const unsigned char* __restrict__ Dh,    // B_N x H_N fp8 (x64)
    const unsigned char* __restrict__ W2T,   // D_N x H_N fp8 (x64)
    float* __restrict__ accum) {
  __shared__ alignas(16) unsigned char As[128 * 128];
  __shared__ alignas(16) unsigned char Bs[128 * 128];
  __shared__ float wsum[4];
  int m_t, n_t;
  xcd_remap(D_N / 128, B_N / 128, m_t, n_t);
  const int m0 = m_t * 128, n0 = n_t * 128;

  f32x4 acc[4][4] = {};
  mx_mainloop<H_N>(Dh, W2T, m0, n0, 121, 121, As, Bs, acc);  // 2^-6 * 2^-6

  const int tid = threadIdx.x;
  const int lane = tid & 63;
  const int wave = tid >> 6;

  float t = 0.0f;
#pragma unroll
  for (int i = 0; i < 4; i++)
#pragma unroll
    for (int j = 0; j < 4; j++)
#pragma unroll
      for (int r = 0; r < 4; r++)
        t += fabsf(acc[i][j][r]);

#pragma unroll
  for (int off2 = 32; off2 > 0; off2 >>= 1)
    t += __shfl_down(t, off2, 64);
  if (lane == 0) wsum[wave] = t;
  __syncthreads();
  if (tid == 0) atomicAdd(accum, wsum[0] + wsum[1] + wsum[2] + wsum[3]);
}

__global__ void finalize_kernel(const float* __restrict__ acc, float* __restrict__ out) {
  out[0] = acc[0] * (1.0f / (float)B_N);
}

extern "C" void kernel_launch(void* const* d_in, const int* in_sizes, int n_in,
                              void* d_out, int out_size, void* d_ws, size_t ws_size,
                              hipStream_t stream) {
  const float* X  = (const float*)d_in[0];
  const float* W1 = (const float*)d_in[1];
  const float* b1 = (const float*)d_in[2];
  const float* W2 = (const float*)d_in[3];
  // d_in[4] = b2 : cancels in the difference
  const int* pci  = (const int*)d_in[5];

  char* ws = (char*)d_ws;
  size_t off = 0;
  unsigned char* Xb  = (unsigned char*)(ws + off); off += (size_t)B_N * D_N;
  unsigned char* W1T = (unsigned char*)(ws + off); off += (size_t)H_N * D_N;
  unsigned char* W2T = (unsigned char*)(ws + off); off += (size_t)D_N * H_N;
  float* w3  = (float*)(ws + off); off += (size_t)H_N * 4;
  float* s   = (float*)(ws + off); off += (size_t)B_N * 4;
  float* acc = (float*)(ws + off); off += 256;
  unsigned char* Dh  = (unsigned char*)(ws + off); off += (size_t)B_N * H_N;
  if (ws_size < off) return;

  hipMemsetAsync(acc, 0, sizeof(float), stream);
  pack_X_kernel<<<B_N * (D_N / 4) / 256, 256, 0, stream>>>((const float4*)X, (int*)Xb, s, pci);
  // W1 is D_N x H_N -> W1T[h][d] = W1[d][h] * 16
  transpose_pack_fp8<<<dim3(H_N / 32, D_N / 32), dim3(32, 8), 0, stream>>>(W1, W1T, D_N, H_N, 16.0f, w3, pci);
  // W2 is H_N x D_N -> W2T[d][h] = W2[h][d] * 64
  transpose_pack_fp8<<<dim3(D_N / 32, H_N / 32), dim3(32, 8), 0, stream>>>(W2, W2T, H_N, D_N, 64.0f, nullptr, nullptr);
  gemm1_dh<<<dim3(H_N / 128, B_N / 128), 256, 0, stream>>>(Xb, W1T, b1, w3, s, Dh);
  gemm2_abs<<<dim3(D_N / 128, B_N / 128), 256, 0, stream>>>(Dh, W2T, acc);
  finalize_kernel<<<1, 1, 0, stream>>>(acc, (float*)d_out);
}

// Round 3
// 310.731 us; speedup vs baseline: 1.7084x; 1.0505x over previous
//
#include <hip/hip_runtime.h>
#include <stdint.h>

#define B_N 16384
#define D_N 1024
#define H_N 4096

typedef int i32x4 __attribute__((ext_vector_type(4)));
typedef int i32x8 __attribute__((ext_vector_type(8)));
typedef float f32x4 __attribute__((ext_vector_type(4)));

__device__ __forceinline__ void gload16(const void* g, void* l) {
  __builtin_amdgcn_global_load_lds((const __attribute__((address_space(1))) void*)g,
                                   (__attribute__((address_space(3))) void*)l,
                                   16, 0, 0);
}

__device__ __forceinline__ unsigned char f2fp8(float v) {
  return (unsigned char)(__builtin_amdgcn_cvt_pk_fp8_f32(v, v, 0, false) & 0xFF);
}

// ================= prep: pack X -> fp8 + s[], transpose W1,W2 -> fp8 =======
// One dispatch. Block ranges:
//   [0, 16384)        : pack X (256 thr, float4 each)
//   [16384, 20480)    : transpose W1 (D_N x H_N) -> W1T (x16), extract w3
//   [20480, 24576)    : transpose W2 (H_N x D_N) -> W2T (x64)
__device__ __forceinline__ void transpose_tile(
    const float* __restrict__ in, unsigned char* __restrict__ out,
    int R, int C, float scale, float* __restrict__ w3, int pci,
    int i0, int j0, int tx, int ty) {
  __shared__ float tile[32][33];
#pragma unroll
  for (int r = 0; r < 32; r += 8) {
    int i = i0 + ty + r;
    int j = j0 + tx;
    float v = in[(size_t)i * C + j];
    tile[ty + r][tx] = v;
    if (w3 != nullptr && i == pci) w3[j] = v;
  }
  __syncthreads();
#pragma unroll
  for (int r = 0; r < 32; r += 8) {
    int jo = j0 + ty + r;
    int io = i0 + tx;
    out[(size_t)jo * R + io] = f2fp8(tile[tx][ty + r] * scale);
  }
}

__global__ __launch_bounds__(256) void prep_kernel(
    const float4* __restrict__ X4, int* __restrict__ Xb,
    float* __restrict__ s,
    const float* __restrict__ W1, unsigned char* __restrict__ W1T, float* __restrict__ w3,
    const float* __restrict__ W2, unsigned char* __restrict__ W2T,
    const int* __restrict__ pci_p) {
  int b = blockIdx.x;
  int tid = threadIdx.x;
  int pci = *pci_p;
  if (b < 16384) {
    int i = b * 256 + tid;
    float4 v = X4[i];
    int p = __builtin_amdgcn_cvt_pk_fp8_f32(v.x, v.y, 0, false);
    p = __builtin_amdgcn_cvt_pk_fp8_f32(v.z, v.w, p, true);
    Xb[i] = p;
    int colg = i & (D_N / 4 - 1);
    if (colg == (pci >> 2)) {
      int row = i >> 8;
      float c;
      switch (pci & 3) {
        case 0:  c = v.x; break;
        case 1:  c = v.y; break;
        case 2:  c = v.z; break;
        default: c = v.w; break;
      }
      s[row] = 1.0f - 2.0f * c;
    }
  } else if (b < 20480) {
    int id = b - 16384;                   // grid (128, 32): j0 over H, i0 over D
    transpose_tile(W1, W1T, D_N, H_N, 16.0f, w3, pci,
                   (id >> 7) * 32, (id & 127) * 32, tid & 31, tid >> 5);
  } else {
    int id = b - 20480;                   // grid (32, 128): j0 over D, i0 over H
    transpose_tile(W2, W2T, H_N, D_N, 64.0f, nullptr, -1,
                   (id >> 5) * 32, (id & 31) * 32, tid & 31, tid >> 5);
  }
}

// ---- MX-fp8 K=128 main loop: C(128x128) += A_tile x B_tile^T over KTOT ----
// LDS XOR-swizzled (global-side scatter; reader XORs back).
template <int KTOT>
__device__ __forceinline__ void mx_mainloop(
    const unsigned char* __restrict__ A, const unsigned char* __restrict__ B,
    int m0, int n0, int sa, int sb,
    unsigned char* As, unsigned char* Bs, f32x4 (&acc)[4][4]) {
  const int tid = threadIdx.x;
  const int lane = tid & 63;
  const int wave = tid >> 6;
  const int wm = (wave >> 1) * 64;
  const int wn = (wave & 1) * 64;
  const int lm = lane & 15;
  const int quad = lane >> 4;

  const int srow = tid >> 3;
  const int clog = (tid & 7) ^ (srow & 7);
  const unsigned char* Ag = A + (size_t)(m0 + srow) * KTOT + clog * 16;
  const unsigned char* Bg = B + (size_t)(n0 + srow) * KTOT + clog * 16;
  unsigned char* As_l = As + tid * 16;
  unsigned char* Bs_l = Bs + tid * 16;

  for (int k0 = 0; k0 < KTOT; k0 += 128) {
#pragma unroll
    for (int it = 0; it < 4; it++) {
      gload16(Ag + k0 + (size_t)(32 * it) * KTOT, As_l + it * 4096);
      gload16(Bg + k0 + (size_t)(32 * it) * KTOT, Bs_l + it * 4096);
    }
    __syncthreads();
    i32x8 a[4], b[4];
#pragma unroll
    for (int i = 0; i < 4; i++) {
      int r = wm + i * 16 + lm;
      int e = r & 7;
      i32x4 lo = *(const i32x4*)&As[r * 128 + ((2 * quad) ^ e) * 16];
      i32x4 hi = *(const i32x4*)&As[r * 128 + ((2 * quad + 1) ^ e) * 16];
      a[i][0] = lo[0]; a[i][1] = lo[1]; a[i][2] = lo[2]; a[i][3] = lo[3];
      a[i][4] = hi[0]; a[i][5] = hi[1]; a[i][6] = hi[2]; a[i][7] = hi[3];
    }
#pragma unroll
    for (int j = 0; j < 4; j++) {
      int r = wn + j * 16 + lm;
      int e = r & 7;
      i32x4 lo = *(const i32x4*)&Bs[r * 128 + ((2 * quad) ^ e) * 16];
      i32x4 hi = *(const i32x4*)&Bs[r * 128 + ((2 * quad + 1) ^ e) * 16];
      b[j][0] = lo[0]; b[j][1] = lo[1]; b[j][2] = lo[2]; b[j][3] = lo[3];
      b[j][4] = hi[0]; b[j][5] = hi[1]; b[j][6] = hi[2]; b[j][7] = hi[3];
    }
#pragma unroll
    for (int i = 0; i < 4; i++)
#pragma unroll
      for (int j = 0; j < 4; j++)
        acc[i][j] = __builtin_amdgcn_mfma_scale_f32_16x16x128_f8f6f4(
            a[i], b[j], acc[i][j], 0, 0, 0, sa, 0, sb);
    __syncthreads();
  }
}

// ---- GEMM1: Z = X @ W1, epilogue Dh = 64*(tanh(z)-tanh(z+s*w3)) -> fp8 ----
// XCD schedule: per XCD x, n-chunks of 8 tiles (1 MB W1T stays L2-hot) with
// all 16 m-panels swept inside each chunk.  m_t = x*16 + m in BOTH gemms so
// Dh panels are produced and consumed on the same XCD's L2.
__global__ __launch_bounds__(256) void gemm1_dh(
    const unsigned char* __restrict__ Xb,    // B_N x D_N fp8 (x1)
    const unsigned char* __restrict__ W1T,   // H_N x D_N fp8 (x16)
    const float* __restrict__ b1,
    const float* __restrict__ w3,            // H_N : W1[pci][h] f32
    const float* __restrict__ s,             // B_N : 1-2*col
    unsigned char* __restrict__ Dh) {        // B_N x H_N fp8 (x64)
  __shared__ alignas(16) unsigned char As[128 * 128];
  __shared__ alignas(16) unsigned char Bs[128 * 128];
  {
  }
  int l = blockIdx.y * gridDim.x + blockIdx.x;  // HW dispatch-linear
  int x = l & 7;                                // XCD round-robin
  int k = l >> 3;                               // 0..511 per XCD
  int ni = k & 7;
  int m  = (k >> 3) & 15;
  int nc = k >> 7;                              // 0..3
  const int m0 = (x * 16 + m) * 128;
  const int n0 = (nc * 8 + ni) * 128;

  f32x4 acc[4][4] = {};
  mx_mainloop<D_N>(Xb, W1T, m0, n0, 127, 123, As, Bs, acc);  // 2^0 * 2^-4

  const int tid = threadIdx.x;
  const int lane = tid & 63;
  const int wave = tid >> 6;
  const int wm = (wave >> 1) * 64;
  const int wn = (wave & 1) * 64;
  const int lm = lane & 15;
  const int quad = lane >> 4;

  // per-column hoists: ews± = e^{±2w}, num± = 128*(1 - e^{±2w})
  float ewp[4], ewm[4], nump[4], numm[4], b1v[4];
  int ghv[4];
#pragma unroll
  for (int j = 0; j < 4; j++) {
    int gh = n0 + wn + j * 16 + lm;
    float w = w3[gh];
    float ep = __expf(2.0f * w);
    float em = __expf(-2.0f * w);
    ewp[j] = ep; ewm[j] = em;
    nump[j] = 128.0f * (1.0f - ep);
    numm[j] = 128.0f * (1.0f - em);
    b1v[j] = b1[gh];
    ghv[j] = gh;
  }
#pragma unroll
  for (int i = 0; i < 4; i++) {
#pragma unroll
    for (int r = 0; r < 4; r++) {
      int gb = m0 + wm + i * 16 + quad * 4 + r;
      bool sp = s[gb] > 0.0f;
      size_t rowbase = (size_t)gb * H_N;
      float o[4];
#pragma unroll
      for (int j = 0; j < 4; j++) {
        float ews = sp ? ewp[j] : ewm[j];
        float num = sp ? nump[j] : numm[j];
        float z = fminf(acc[i][j][r] + b1v[j], 12.0f);
        float E = __expf(2.0f * z);
        float den = (E * ews + 1.0f) * (E + 1.0f);
        // stored = 64*dh = E * 128(1-ews) / den
        o[j] = (E * num) * __builtin_amdgcn_rcpf(den);
      }
      int p01 = __builtin_amdgcn_cvt_pk_fp8_f32(o[0], o[1], 0, false);
      int p23 = __builtin_amdgcn_cvt_pk_fp8_f32(o[2], o[3], 0, false);
      Dh[rowbase + ghv[0]] = (unsigned char)(p01 & 0xFF);
      Dh[rowbase + ghv[1]] = (unsigned char)((p01 >> 8) & 0xFF);
      Dh[rowbase + ghv[2]] = (unsigned char)(p23 & 0xFF);
      Dh[rowbase + ghv[3]] = (unsigned char)((p23 >> 8) & 0xFF);
    }
  }
}

// ---- GEMM2: Y = Dh @ W2, epilogue mean-scaled sum|Y| -> atomic d_out ----
__global__ __launch_bounds__(256) void gemm2_abs(
    const unsigned char* __restrict__ Dh,    // B_N x H_N fp8 (x64)
    const unsigned char* __restrict__ W2T,   // D_N x H_N fp8 (x64)
    float* __restrict__ out) {
  __shared__ alignas(16) unsigned char As[128 * 128];
  __shared__ alignas(16) unsigned char Bs[128 * 128];
  __shared__ float wsum[4];
  int l = blockIdx.y * gridDim.x + blockIdx.x;
  int x = l & 7;
  int k = l >> 3;                               // 0..127 per XCD
  int ni = k & 7;
  int m  = k >> 3;                              // 0..15
  const int m0 = (x * 16 + m) * 128;            // same m<->XCD map as gemm1
  const int n0 = ni * 128;

  f32x4 acc[4][4] = {};
  mx_mainloop<H_N>(Dh, W2T, m0, n0, 121, 121, As, Bs, acc);  // 2^-6 * 2^-6

  const int tid = threadIdx.x;
  const int lane = tid & 63;
  const int wave = tid >> 6;

  float t = 0.0f;
#pragma unroll
  for (int i = 0; i < 4; i++)
#pragma unroll
    for (int j = 0; j < 4; j++)
#pragma unroll
      for (int r = 0; r < 4; r++)
        t += fabsf(acc[i][j][r]);

#pragma unroll
  for (int off2 = 32; off2 > 0; off2 >>= 1)
    t += __shfl_down(t, off2, 64);
  if (lane == 0) wsum[wave] = t;
  __syncthreads();
  if (tid == 0)
    atomicAdd(out, (wsum[0] + wsum[1] + wsum[2] + wsum[3]) * (1.0f / (float)B_N));
}

extern "C" void kernel_launch(void* const* d_in, const int* in_sizes, int n_in,
                              void* d_out, int out_size, void* d_ws, size_t ws_size,
                              hipStream_t stream) {
  const float* X  = (const float*)d_in[0];
  const float* W1 = (const float*)d_in[1];
  const float* b1 = (const float*)d_in[2];
  const float* W2 = (const float*)d_in[3];
  // d_in[4] = b2 : cancels in the difference
  const int* pci  = (const int*)d_in[5];

  char* ws = (char*)d_ws;
  size_t off = 0;
  unsigned char* Xb  = (unsigned char*)(ws + off); off += (size_t)B_N * D_N;
  unsigned char* W1T = (unsigned char*)(ws + off); off += (size_t)H_N * D_N;
  unsigned char* W2T = (unsigned char*)(ws + off); off += (size_t)D_N * H_N;
  float* w3  = (float*)(ws + off); off += (size_t)H_N * 4;
  float* s   = (float*)(ws + off); off += (size_t)B_N * 4;
  unsigned char* Dh  = (unsigned char*)(ws + off); off += (size_t)B_N * H_N;
  if (ws_size < off) return;

  hipMemsetAsync(d_out, 0, sizeof(float), stream);
  prep_kernel<<<24576, 256, 0, stream>>>((const float4*)X, (int*)Xb, s,
                                         W1, W1T, w3, W2, W2T, pci);
  gemm1_dh<<<dim3(32, 128), 256, 0, stream>>>(Xb, W1T, b1, w3, s, Dh);
  gemm2_abs<<<dim3(8, 128), 256, 0, stream>>>(Dh, W2T, (float*)d_out);
}

// Round 4
// 309.016 us; speedup vs baseline: 1.7179x; 1.0056x over previous
//
#include <hip/hip_runtime.h>
#include <stdint.h>

#define B_N 16384
#define D_N 1024
#define H_N 4096

typedef int i32x4 __attribute__((ext_vector_type(4)));
typedef int i32x8 __attribute__((ext_vector_type(8)));
typedef float f32x4 __attribute__((ext_vector_type(4)));

__device__ __forceinline__ void gload16(const void* g, void* l) {
  __builtin_amdgcn_global_load_lds((const __attribute__((address_space(1))) void*)g,
                                   (__attribute__((address_space(3))) void*)l,
                                   16, 0, 0);
}

__device__ __forceinline__ unsigned char f2fp8(float v) {
  return (unsigned char)(__builtin_amdgcn_cvt_pk_fp8_f32(v, v, 0, false) & 0xFF);
}

// within-64-block H permutation used for Dh stores / W2T K-index:
// u = j*16+lm  ->  lm*4+j
__device__ __forceinline__ int perm_h(int h) {
  return (h & ~63) | ((h & 15) << 2) | ((h >> 4) & 3);
}

// ================= prep A: pack X -> fp8 (x1), s[], zero d_out =============
__global__ __launch_bounds__(256) void pack_x_kernel(
    const float4* __restrict__ X4, int* __restrict__ Xb,
    float* __restrict__ s, const int* __restrict__ pci_p,
    float* __restrict__ out0) {
  int i = (blockIdx.x * 256 + threadIdx.x) * 2;
  if (blockIdx.x == 0 && threadIdx.x == 0) out0[0] = 0.0f;  // replaces memset
  int pci = *pci_p;
#pragma unroll
  for (int u = 0; u < 2; u++) {
    float4 v = X4[i + u];
    int p = __builtin_amdgcn_cvt_pk_fp8_f32(v.x, v.y, 0, false);
    p = __builtin_amdgcn_cvt_pk_fp8_f32(v.z, v.w, p, true);
    Xb[i + u] = p;
    if (((i + u) & (D_N / 4 - 1)) == (pci >> 2)) {
      int row = (i + u) >> 8;
      float c;
      switch (pci & 3) {
        case 0:  c = v.x; break;
        case 1:  c = v.y; break;
        case 2:  c = v.z; break;
        default: c = v.w; break;
      }
      s[row] = 1.0f - 2.0f * c;
    }
  }
}

// ================= prep B: transpose W1,W2 -> fp8 ==========================
__device__ __forceinline__ void transpose_tile(
    const float* __restrict__ in, unsigned char* __restrict__ out,
    int R, int C, float scale, float* __restrict__ w3, int pci,
    int i0, int j0, int tx, int ty, bool permute) {
  __shared__ float tile[32][33];
#pragma unroll
  for (int r = 0; r < 32; r += 8) {
    int i = i0 + ty + r;
    int j = j0 + tx;
    float v = in[(size_t)i * C + j];
    tile[ty + r][tx] = v;
    if (w3 != nullptr && i == pci) w3[j] = v;
  }
  __syncthreads();
#pragma unroll
  for (int r = 0; r < 32; r += 8) {
    int jo = j0 + ty + r;
    int io = i0 + tx;
    int ioo = permute ? perm_h(io) : io;
    out[(size_t)jo * R + ioo] = f2fp8(tile[tx][ty + r] * scale);
  }
}

__global__ __launch_bounds__(256) void transpose_kernel(
    const float* __restrict__ W1, unsigned char* __restrict__ W1T, float* __restrict__ w3,
    const float* __restrict__ W2, unsigned char* __restrict__ W2T,
    const int* __restrict__ pci_p) {
  int b = blockIdx.x;
  int tid = threadIdx.x;
  int pci = *pci_p;
  if (b < 4096) {
    // W1 (D_N x H_N) -> W1T[h][d] = W1[d][h]*16 ; rows h NOT permuted
    transpose_tile(W1, W1T, D_N, H_N, 16.0f, w3, pci,
                   (b >> 7) * 32, (b & 127) * 32, tid & 31, tid >> 5, false);
  } else {
    // W2 (H_N x D_N) -> W2T[d][perm(h)] = W2[h][d]*64 ; K(=H) permuted
    int id = b - 4096;
    transpose_tile(W2, W2T, H_N, D_N, 64.0f, nullptr, -1,
                   (id >> 5) * 32, (id & 31) * 32, tid & 31, tid >> 5, true);
  }
}

// ---- MX-fp8 K=128 main loop: C(128x128) += A_tile x B_tile^T over KTOT ----
// LDS XOR-swizzled on the global gather side; reader XORs back; fragments
// assembled via shufflevector so ds_read_b128 lands directly in i32x8 halves.
template <int KTOT>
__device__ __forceinline__ void mx_mainloop(
    const unsigned char* __restrict__ A, const unsigned char* __restrict__ B,
    int m0, int n0, int sa, int sb,
    unsigned char* As, unsigned char* Bs, f32x4 (&acc)[4][4]) {
  const int tid = threadIdx.x;
  const int lane = tid & 63;
  const int wave = tid >> 6;
  const int wm = (wave >> 1) * 64;
  const int wn = (wave & 1) * 64;
  const int lm = lane & 15;
  const int quad = lane >> 4;

  const int srow = tid >> 3;
  const int clog = (tid & 7) ^ (srow & 7);
  const unsigned char* Ag = A + (size_t)(m0 + srow) * KTOT + clog * 16;
  const unsigned char* Bg = B + (size_t)(n0 + srow) * KTOT + clog * 16;
  unsigned char* As_l = As + tid * 16;
  unsigned char* Bs_l = Bs + tid * 16;

  for (int k0 = 0; k0 < KTOT; k0 += 128) {
#pragma unroll
    for (int it = 0; it < 4; it++) {
      gload16(Ag + k0 + (size_t)(32 * it) * KTOT, As_l + it * 4096);
      gload16(Bg + k0 + (size_t)(32 * it) * KTOT, Bs_l + it * 4096);
    }
    __syncthreads();
    i32x8 a[4], b[4];
#pragma unroll
    for (int i = 0; i < 4; i++) {
      int r = wm + i * 16 + lm;
      int e = r & 7;
      i32x4 lo = *(const i32x4*)&As[r * 128 + ((2 * quad) ^ e) * 16];
      i32x4 hi = *(const i32x4*)&As[r * 128 + ((2 * quad + 1) ^ e) * 16];
      a[i] = __builtin_shufflevector(lo, hi, 0, 1, 2, 3, 4, 5, 6, 7);
    }
#pragma unroll
    for (int j = 0; j < 4; j++) {
      int r = wn + j * 16 + lm;
      int e = r & 7;
      i32x4 lo = *(const i32x4*)&Bs[r * 128 + ((2 * quad) ^ e) * 16];
      i32x4 hi = *(const i32x4*)&Bs[r * 128 + ((2 * quad + 1) ^ e) * 16];
      b[j] = __builtin_shufflevector(lo, hi, 0, 1, 2, 3, 4, 5, 6, 7);
    }
#pragma unroll
    for (int i = 0; i < 4; i++)
#pragma unroll
      for (int j = 0; j < 4; j++)
        acc[i][j] = __builtin_amdgcn_mfma_scale_f32_16x16x128_f8f6f4(
            a[i], b[j], acc[i][j], 0, 0, 0, sa, 0, sb);
    __syncthreads();
  }
}

// ---- GEMM1: Z = X @ W1, epilogue Dh = 64*(tanh(z)-tanh(z+s*w3)) -> fp8 ----
// Schedule: per XCD x, n-chunks of 8 tiles (1 MB W1T L2-hot), 16 m-panels per
// chunk. m_t = x*16+m in BOTH gemms so Dh panels stay on one XCD's L2.
// Dh stored with perm_h column layout -> one coalesced dword store per 4 cols.
__global__ __launch_bounds__(256) void gemm1_dh(
    const unsigned char* __restrict__ Xb,    // B_N x D_N fp8 (x1)
    const unsigned char* __restrict__ W1T,   // H_N x D_N fp8 (x16)
    const float* __restrict__ b1,
    const float* __restrict__ w3,            // H_N : W1[pci][h] f32
    const float* __restrict__ s,             // B_N : 1-2*col
    unsigned int* __restrict__ Dh4) {        // B_N x H_N fp8 (x64), perm'd cols
  __shared__ alignas(16) unsigned char As[128 * 128];
  __shared__ alignas(16) unsigned char Bs[128 * 128];
  int l = blockIdx.y * gridDim.x + blockIdx.x;  // HW dispatch-linear
  int x = l & 7;                                // XCD round-robin
  int k = l >> 3;                               // 0..511 per XCD
  int ni = k & 7;
  int m  = (k >> 3) & 15;
  int nc = k >> 7;                              // 0..3
  const int m0 = (x * 16 + m) * 128;
  const int n0 = (nc * 8 + ni) * 128;

  f32x4 acc[4][4] = {};
  mx_mainloop<D_N>(Xb, W1T, m0, n0, 127, 123, As, Bs, acc);  // 2^0 * 2^-4

  const int tid = threadIdx.x;
  const int lane = tid & 63;
  const int wave = tid >> 6;
  const int wm = (wave >> 1) * 64;
  const int wn = (wave & 1) * 64;
  const int lm = lane & 15;
  const int quad = lane >> 4;

  float ewp[4], ewm[4], nump[4], numm[4], b1v[4];
#pragma unroll
  for (int j = 0; j < 4; j++) {
    int gh = n0 + wn + j * 16 + lm;
    float w = w3[gh];
    float ep = __expf(2.0f * w);
    float em = __expf(-2.0f * w);
    ewp[j] = ep; ewm[j] = em;
    nump[j] = 128.0f * (1.0f - ep);
    numm[j] = 128.0f * (1.0f - em);
    b1v[j] = b1[gh];
  }
  const size_t coloff = (size_t)((n0 + wn) >> 2) + lm;
#pragma unroll
  for (int i = 0; i < 4; i++) {
#pragma unroll
    for (int r = 0; r < 4; r++) {
      int gb = m0 + wm + i * 16 + quad * 4 + r;
      bool sp = s[gb] > 0.0f;
      float o[4];
#pragma unroll
      for (int j = 0; j < 4; j++) {
        float ews = sp ? ewp[j] : ewm[j];
        float num = sp ? nump[j] : numm[j];
        float z = fminf(acc[i][j][r] + b1v[j], 12.0f);
        float E = __expf(2.0f * z);
        float den = (E * ews + 1.0f) * (E + 1.0f);
        o[j] = (E * num) * __builtin_amdgcn_rcpf(den);  // 64*dh
      }
      int p = __builtin_amdgcn_cvt_pk_fp8_f32(o[0], o[1], 0, false);
      p = __builtin_amdgcn_cvt_pk_fp8_f32(o[2], o[3], p, true);
      Dh4[(size_t)gb * (H_N / 4) + coloff] = (unsigned int)p;
    }
  }
}

// ---- GEMM2: Y = Dh @ W2, epilogue mean-scaled sum|Y| -> atomic d_out ----
// Schedule: per XCD, 2 ni-chunks of 4 (2 MB W2T anchor L2-hot); within a
// chunk sweep m with 4 consecutive blocks sharing one Dh panel.
__global__ __launch_bounds__(256) void gemm2_abs(
    const unsigned char* __restrict__ Dh,    // B_N x H_N fp8 (x64), perm'd K
    const unsigned char* __restrict__ W2T,   // D_N x H_N fp8 (x64), perm'd K
    float* __restrict__ out) {
  __shared__ alignas(16) unsigned char As[128 * 128];
  __shared__ alignas(16) unsigned char Bs[128 * 128];
  __shared__ float wsum[4];
  int l = blockIdx.y * gridDim.x + blockIdx.x;
  int x = l & 7;
  int k = l >> 3;                               // 0..127 per XCD
  int c = k >> 6;                               // ni-chunk 0..1
  int idx = k & 63;
  int m  = idx >> 2;                            // 0..15 (same m<->XCD map)
  int nj = idx & 3;
  const int m0 = (x * 16 + m) * 128;
  const int n0 = (c * 4 + nj) * 128;

  f32x4 acc[4][4] = {};
  mx_mainloop<H_N>(Dh, W2T, m0, n0, 121, 121, As, Bs, acc);  // 2^-6 * 2^-6

  const int tid = threadIdx.x;
  const int lane = tid & 63;
  const int wave = tid >> 6;

  float t = 0.0f;
#pragma unroll
  for (int i = 0; i < 4; i++)
#pragma unroll
    for (int j = 0; j < 4; j++)
#pragma unroll
      for (int r = 0; r < 4; r++)
        t += fabsf(acc[i][j][r]);

#pragma unroll
  for (int off2 = 32; off2 > 0; off2 >>= 1)
    t += __shfl_down(t, off2, 64);
  if (lane == 0) wsum[wave] = t;
  __syncthreads();
  if (tid == 0)
    atomicAdd(out, (wsum[0] + wsum[1] + wsum[2] + wsum[3]) * (1.0f / (float)B_N));
}

extern "C" void kernel_launch(void* const* d_in, const int* in_sizes, int n_in,
                              void* d_out, int out_size, void* d_ws, size_t ws_size,
                              hipStream_t stream) {
  const float* X  = (const float*)d_in[0];
  const float* W1 = (const float*)d_in[1];
  const float* b1 = (const float*)d_in[2];
  const float* W2 = (const float*)d_in[3];
  // d_in[4] = b2 : cancels in the difference
  const int* pci  = (const int*)d_in[5];

  char* ws = (char*)d_ws;
  size_t off = 0;
  unsigned char* Xb  = (unsigned char*)(ws + off); off += (size_t)B_N * D_N;
  unsigned char* W1T = (unsigned char*)(ws + off); off += (size_t)H_N * D_N;
  unsigned char* W2T = (unsigned char*)(ws + off); off += (size_t)D_N * H_N;
  float* w3  = (float*)(ws + off); off += (size_t)H_N * 4;
  float* s   = (float*)(ws + off); off += (size_t)B_N * 4;
  unsigned char* Dh  = (unsigned char*)(ws + off); off += (size_t)B_N * H_N;
  if (ws_size < off) return;

  pack_x_kernel<<<8192, 256, 0, stream>>>((const float4*)X, (int*)Xb, s, pci,
                                          (float*)d_out);
  transpose_kernel<<<8192, 256, 0, stream>>>(W1, W1T, w3, W2, W2T, pci);
  gemm1_dh<<<dim3(32, 128), 256, 0, stream>>>(Xb, W1T, b1, w3, s,
                                              (unsigned int*)Dh);
  gemm2_abs<<<dim3(8, 128), 256, 0, stream>>>(Dh, W2T, (float*)d_out);
}

// Round 5
// 283.443 us; speedup vs baseline: 1.8728x; 1.0902x over previous
//
#include <hip/hip_runtime.h>
#include <stdint.h>

#define B_N 16384
#define D_N 1024
#define H_N 4096

typedef int i32x4 __attribute__((ext_vector_type(4)));
typedef int i32x8 __attribute__((ext_vector_type(8)));
typedef float f32x4 __attribute__((ext_vector_type(4)));

__device__ __forceinline__ void gload16(const void* g, void* l) {
  __builtin_amdgcn_global_load_lds((const __attribute__((address_space(1))) void*)g,
                                   (__attribute__((address_space(3))) void*)l,
                                   16, 0, 0);
}

__device__ __forceinline__ unsigned char f2fp8(float v) {
  return (unsigned char)(__builtin_amdgcn_cvt_pk_fp8_f32(v, v, 0, false) & 0xFF);
}

// within-64-block H permutation used for Dh stores / W2T K-index:
// u = j*16+lm  ->  lm*4+j
__device__ __forceinline__ int perm_h(int h) {
  return (h & ~63) | ((h & 15) << 2) | ((h >> 4) & 3);
}

// ================= prep (single dispatch): pack X, transpose W1/W2 =========
__device__ __forceinline__ void transpose_tile(
    const float* __restrict__ in, unsigned char* __restrict__ out,
    int R, int C, float scale, float* __restrict__ w3, int pci,
    int i0, int j0, int tx, int ty, bool permute) {
  __shared__ float tile[32][33];
#pragma unroll
  for (int r = 0; r < 32; r += 8) {
    int i = i0 + ty + r;
    int j = j0 + tx;
    float v = in[(size_t)i * C + j];
    tile[ty + r][tx] = v;
    if (w3 != nullptr && i == pci) w3[j] = v;
  }
  __syncthreads();
#pragma unroll
  for (int r = 0; r < 32; r += 8) {
    int jo = j0 + ty + r;
    int io = i0 + tx;
    int ioo = permute ? perm_h(io) : io;
    out[(size_t)jo * R + ioo] = f2fp8(tile[tx][ty + r] * scale);
  }
}

__global__ __launch_bounds__(256) void prep_kernel(
    const float4* __restrict__ X4, int* __restrict__ Xb,
    float* __restrict__ s,
    const float* __restrict__ W1, unsigned char* __restrict__ W1T, float* __restrict__ w3,
    const float* __restrict__ W2, unsigned char* __restrict__ W2T,
    const int* __restrict__ pci_p, float* __restrict__ out0) {
  int b = blockIdx.x;
  int tid = threadIdx.x;
  int pci = *pci_p;
  if (b == 0 && tid == 0) out0[0] = 0.0f;   // zero the output accumulator
  if (b < 8192) {
    int i = (b * 256 + tid) * 2;
#pragma unroll
    for (int u = 0; u < 2; u++) {
      float4 v = X4[i + u];
      int p = __builtin_amdgcn_cvt_pk_fp8_f32(v.x, v.y, 0, false);
      p = __builtin_amdgcn_cvt_pk_fp8_f32(v.z, v.w, p, true);
      Xb[i + u] = p;
      if (((i + u) & (D_N / 4 - 1)) == (pci >> 2)) {
        int row = (i + u) >> 8;
        float c;
        switch (pci & 3) {
          case 0:  c = v.x; break;
          case 1:  c = v.y; break;
          case 2:  c = v.z; break;
          default: c = v.w; break;
        }
        s[row] = 1.0f - 2.0f * c;
      }
    }
  } else if (b < 12288) {
    // W1 (D_N x H_N) -> W1T[h][d] = W1[d][h]*16 ; rows h NOT permuted
    int id = b - 8192;
    transpose_tile(W1, W1T, D_N, H_N, 16.0f, w3, pci,
                   (id >> 7) * 32, (id & 127) * 32, tid & 31, tid >> 5, false);
  } else {
    // W2 (H_N x D_N) -> W2T[d][perm(h)] = W2[h][d]*64 ; K(=H) permuted
    int id = b - 12288;
    transpose_tile(W2, W2T, H_N, D_N, 64.0f, nullptr, -1,
                   (id >> 5) * 32, (id & 31) * 32, tid & 31, tid >> 5, true);
  }
}

// ---- MX-fp8 K=128 main loop: C(128x128) += A_tile x B_tile^T over KTOT ----
// LDS XOR-swizzled on the global gather side; reader XORs back.
// Register-lean: hold b[0..3] (32 VGPR) + one a fragment (8) so that with the
// 64-AGPR accumulator the kernel fits 128 regs -> 4 waves/SIMD (lb 256,4).
template <int KTOT>
__device__ __forceinline__ void mx_mainloop(
    const unsigned char* __restrict__ A, const unsigned char* __restrict__ B,
    int m0, int n0, int sa, int sb,
    unsigned char* As, unsigned char* Bs, f32x4 (&acc)[4][4]) {
  const int tid = threadIdx.x;
  const int lane = tid & 63;
  const int wave = tid >> 6;
  const int wm = (wave >> 1) * 64;
  const int wn = (wave & 1) * 64;
  const int lm = lane & 15;
  const int quad = lane >> 4;

  const int srow = tid >> 3;
  const int clog = (tid & 7) ^ (srow & 7);
  const unsigned char* Ag = A + (size_t)(m0 + srow) * KTOT + clog * 16;
  const unsigned char* Bg = B + (size_t)(n0 + srow) * KTOT + clog * 16;
  unsigned char* As_l = As + tid * 16;
  unsigned char* Bs_l = Bs + tid * 16;

  for (int k0 = 0; k0 < KTOT; k0 += 128) {
#pragma unroll
    for (int it = 0; it < 4; it++) {
      gload16(Ag + k0 + (size_t)(32 * it) * KTOT, As_l + it * 4096);
      gload16(Bg + k0 + (size_t)(32 * it) * KTOT, Bs_l + it * 4096);
    }
    __syncthreads();
    i32x8 b[4];
#pragma unroll
    for (int j = 0; j < 4; j++) {
      int r = wn + j * 16 + lm;
      int e = r & 7;
      i32x4 lo = *(const i32x4*)&Bs[r * 128 + ((2 * quad) ^ e) * 16];
      i32x4 hi = *(const i32x4*)&Bs[r * 128 + ((2 * quad + 1) ^ e) * 16];
      b[j] = __builtin_shufflevector(lo, hi, 0, 1, 2, 3, 4, 5, 6, 7);
    }
#pragma unroll
    for (int i = 0; i < 4; i++) {
      int r = wm + i * 16 + lm;
      int e = r & 7;
      i32x4 lo = *(const i32x4*)&As[r * 128 + ((2 * quad) ^ e) * 16];
      i32x4 hi = *(const i32x4*)&As[r * 128 + ((2 * quad + 1) ^ e) * 16];
      i32x8 av = __builtin_shufflevector(lo, hi, 0, 1, 2, 3, 4, 5, 6, 7);
#pragma unroll
      for (int j = 0; j < 4; j++)
        acc[i][j] = __builtin_amdgcn_mfma_scale_f32_16x16x128_f8f6f4(
            av, b[j], acc[i][j], 0, 0, 0, sa, 0, sb);
    }
    __syncthreads();
  }
}

// ---- GEMM1: Z = X @ W1, epilogue Dh = 64*(tanh(z)-tanh(z+s*w3)) -> fp8 ----
// Schedule: per XCD x, n-chunks of 8 tiles (1 MB W1T L2-hot), 16 m-panels per
// chunk. m_t = x*16+m in BOTH gemms so Dh panels stay on one XCD's L2.
// Grid 4096 = 4 exact generations at 4 blocks/CU.
__global__ __launch_bounds__(256, 4) void gemm1_dh(
    const unsigned char* __restrict__ Xb,    // B_N x D_N fp8 (x1)
    const unsigned char* __restrict__ W1T,   // H_N x D_N fp8 (x16)
    const float* __restrict__ b1,
    const float* __restrict__ w3,            // H_N : W1[pci][h] f32
    const float* __restrict__ s,             // B_N : 1-2*col
    unsigned int* __restrict__ Dh4) {        // B_N x H_N fp8 (x64), perm'd cols
  __shared__ alignas(16) unsigned char As[128 * 128];
  __shared__ alignas(16) unsigned char Bs[128 * 128];
  int l = blockIdx.y * gridDim.x + blockIdx.x;  // HW dispatch-linear
  int x = l & 7;                                // XCD round-robin
  int k = l >> 3;                               // 0..511 per XCD
  int ni = k & 7;
  int m  = (k >> 3) & 15;
  int nc = k >> 7;                              // 0..3
  const int m0 = (x * 16 + m) * 128;
  const int n0 = (nc * 8 + ni) * 128;

  f32x4 acc[4][4] = {};
  mx_mainloop<D_N>(Xb, W1T, m0, n0, 127, 123, As, Bs, acc);  // 2^0 * 2^-4

  const int tid = threadIdx.x;
  const int lane = tid & 63;
  const int wave = tid >> 6;
  const int wm = (wave >> 1) * 64;
  const int wn = (wave & 1) * 64;
  const int lm = lane & 15;
  const int quad = lane >> 4;

  float ewp[4], ewm[4], nump[4], numm[4], b1v[4];
#pragma unroll
  for (int j = 0; j < 4; j++) {
    int gh = n0 + wn + j * 16 + lm;
    float w = w3[gh];
    float ep = __expf(2.0f * w);
    float em = __expf(-2.0f * w);
    ewp[j] = ep; ewm[j] = em;
    nump[j] = 128.0f * (1.0f - ep);
    numm[j] = 128.0f * (1.0f - em);
    b1v[j] = b1[gh];
  }
  const size_t coloff = (size_t)((n0 + wn) >> 2) + lm;
#pragma unroll
  for (int i = 0; i < 4; i++) {
#pragma unroll
    for (int r = 0; r < 4; r++) {
      int gb = m0 + wm + i * 16 + quad * 4 + r;
      bool sp = s[gb] > 0.0f;
      float o[4];
#pragma unroll
      for (int j = 0; j < 4; j++) {
        float ews = sp ? ewp[j] : ewm[j];
        float num = sp ? nump[j] : numm[j];
        float z = fminf(acc[i][j][r] + b1v[j], 12.0f);
        float E = __expf(2.0f * z);
        float den = (E * ews + 1.0f) * (E + 1.0f);
        o[j] = (E * num) * __builtin_amdgcn_rcpf(den);  // 64*dh
      }
      int p = __builtin_amdgcn_cvt_pk_fp8_f32(o[0], o[1], 0, false);
      p = __builtin_amdgcn_cvt_pk_fp8_f32(o[2], o[3], p, true);
      Dh4[(size_t)gb * (H_N / 4) + coloff] = (unsigned int)p;
    }
  }
}

// ---- GEMM2: Y = Dh @ W2, epilogue mean-scaled sum|Y| -> atomic d_out ----
// Grid 1024 = ONE exact generation at 4 blocks/CU.
__global__ __launch_bounds__(256, 4) void gemm2_abs(
    const unsigned char* __restrict__ Dh,    // B_N x H_N fp8 (x64), perm'd K
    const unsigned char* __restrict__ W2T,   // D_N x H_N fp8 (x64), perm'd K
    float* __restrict__ out) {
  __shared__ alignas(16) unsigned char As[128 * 128];
  __shared__ alignas(16) unsigned char Bs[128 * 128];
  __shared__ float wsum[4];
  int l = blockIdx.y * gridDim.x + blockIdx.x;
  int x = l & 7;
  int k = l >> 3;                               // 0..127 per XCD
  int c = k >> 6;                               // ni-chunk 0..1
  int idx = k & 63;
  int m  = idx >> 2;                            // 0..15 (same m<->XCD map)
  int nj = idx & 3;
  const int m0 = (x * 16 + m) * 128;
  const int n0 = (c * 4 + nj) * 128;

  f32x4 acc[4][4] = {};
  mx_mainloop<H_N>(Dh, W2T, m0, n0, 121, 121, As, Bs, acc);  // 2^-6 * 2^-6

  const int tid = threadIdx.x;
  const int lane = tid & 63;
  const int wave = tid >> 6;

  float t = 0.0f;
#pragma unroll
  for (int i = 0; i < 4; i++)
#pragma unroll
    for (int j = 0; j < 4; j++)
#pragma unroll
      for (int r = 0; r < 4; r++)
        t += fabsf(acc[i][j][r]);

#pragma unroll
  for (int off2 = 32; off2 > 0; off2 >>= 1)
    t += __shfl_down(t, off2, 64);
  if (lane == 0) wsum[wave] = t;
  __syncthreads();
  if (tid == 0)
    atomicAdd(out, (wsum[0] + wsum[1] + wsum[2] + wsum[3]) * (1.0f / (float)B_N));
}

extern "C" void kernel_launch(void* const* d_in, const int* in_sizes, int n_in,
                              void* d_out, int out_size, void* d_ws, size_t ws_size,
                              hipStream_t stream) {
  const float* X  = (const float*)d_in[0];
  const float* W1 = (const float*)d_in[1];
  const float* b1 = (const float*)d_in[2];
  const float* W2 = (const float*)d_in[3];
  // d_in[4] = b2 : cancels in the difference
  const int* pci  = (const int*)d_in[5];

  char* ws = (char*)d_ws;
  size_t off = 0;
  unsigned char* Xb  = (unsigned char*)(ws + off); off += (size_t)B_N * D_N;
  unsigned char* W1T = (unsigned char*)(ws + off); off += (size_t)H_N * D_N;
  unsigned char* W2T = (unsigned char*)(ws + off); off += (size_t)D_N * H_N;
  float* w3  = (float*)(ws + off); off += (size_t)H_N * 4;
  float* s   = (float*)(ws + off); off += (size_t)B_N * 4;
  unsigned char* Dh  = (unsigned char*)(ws + off); off += (size_t)B_N * H_N;
  if (ws_size < off) return;

  prep_kernel<<<16384, 256, 0, stream>>>((const float4*)X, (int*)Xb, s,
                                         W1, W1T, w3, W2, W2T, pci,
                                         (float*)d_out);
  gemm1_dh<<<dim3(32, 128), 256, 0, stream>>>(Xb, W1T, b1, w3, s,
                                              (unsigned int*)Dh);
  gemm2_abs<<<dim3(8, 128), 256, 0, stream>>>(Dh, W2T, (float*)d_out);
}